// Round 7
// baseline (401.297 us; speedup 1.0000x reference)
//
#include <hip/hip_runtime.h>

#define NB 4
#define NN 4096
#define NE 65536
#define DIN 128
#define DB 64
#define DOUT 128
#define NT 4
#define DCAT 320

#define MT 64               // edges per tile
#define LDH (DOUT + 8)      // 136 elems, 272 B row stride (16-div)

typedef __bf16 bf16;
typedef __bf16 bf16x2 __attribute__((ext_vector_type(2)));
typedef __bf16 bf16x4 __attribute__((ext_vector_type(4)));
typedef __bf16 bf16x8 __attribute__((ext_vector_type(8)));
typedef float floatx4 __attribute__((ext_vector_type(4)));

// ---------------- prep: zero counters, sites fp32->bf16, weight repack, bonds fp32->bf16
#define NS4 (NB * NN * DIN / 4)      // 524288 float4 groups
#define NA  (NT * 256 * DCAT)        // 327680 WtA elems
#define NB2 (NT * 256 * DOUT)        // 131072 WtB elems
#define NBO4 (NB * NE * DB / 4)      // 4194304 bond float4 groups
#define NZERO 8208                   // cnt(4+12pad) + deg(4096) + cursor(4096) ints
__global__ void prep_k(const float* __restrict__ sites, const float* __restrict__ bonds,
                       const float* __restrict__ W1a, const float* __restrict__ W2a,
                       const float* __restrict__ W1b, const float* __restrict__ W2b,
                       bf16* __restrict__ sitesB,
                       bf16* __restrict__ WtA, bf16* __restrict__ WtB,
                       bf16* __restrict__ bondsB,
                       int* __restrict__ zeroRegion) {
    int i = blockIdx.x * 256 + threadIdx.x;
    if (i < NZERO) zeroRegion[i] = 0;
    if (i < NS4) {
        float4 f = ((const float4*)sites)[i];
        bf16x4 h = { (bf16)f.x, (bf16)f.y, (bf16)f.z, (bf16)f.w };
        ((bf16x4*)sitesB)[i] = h;
    } else if (i < NS4 + NA) {
        int j = i - NS4;
        int k = j % DCAT;
        int n = (j / DCAT) % 256;
        int t = j / (DCAT * 256);
        float w = (n < DOUT) ? W1a[(t * DCAT + k) * DOUT + n]
                             : W2a[(t * DCAT + k) * DOUT + (n - DOUT)];
        WtA[j] = (bf16)w;
    } else if (i < NS4 + NA + NB2) {
        int j = i - NS4 - NA;
        int k = j % DOUT;
        int n = (j / DOUT) % 256;
        int t = j / (DOUT * 256);
        float w = (n < DOUT) ? W1b[(t * DOUT + k) * DOUT + n]
                             : W2b[(t * DOUT + k) * DOUT + (n - DOUT)];
        WtB[j] = (bf16)w;
    } else {
        int j = i - NS4 - NA - NB2;
        float4 f = ((const float4*)bonds)[j];
        bf16x4 h = { (bf16)f.x, (bf16)f.y, (bf16)f.z, (bf16)f.w };
        ((bf16x4*)bondsB)[j] = h;
    }
}

// ---------------- bucket edges by type (LDS histogram) + degree count for idx2 CSR
__global__ void bucket_k(const int* __restrict__ uc, const int* __restrict__ idx2,
                         int* __restrict__ cnt, int* __restrict__ deg,
                         int* __restrict__ bucket) {
    __shared__ int h[NT];
    __shared__ int baseo[NT];
    int tid = threadIdx.x;
    if (tid < NT) h[tid] = 0;
    __syncthreads();
    int e = blockIdx.x * 256 + tid;
    int t = uc[e] & 3;
    int lp = atomicAdd(&h[t], 1);         // LDS atomic
    __syncthreads();
    if (tid < NT) baseo[tid] = atomicAdd(&cnt[tid], h[tid]);
    __syncthreads();
    bucket[t * NE + baseo[t] + lp] = e;
    atomicAdd(&deg[idx2[e] & (NN - 1)], 1);
}

// ---------------- exclusive prefix sum deg[4096] -> off[4097]; 256 thr, shuffle scan
__global__ void scan_k(const int* __restrict__ deg, int* __restrict__ off) {
    __shared__ int wsum[4];
    int tid = threadIdx.x;                // 256 threads, each owns 16 elems
    int lane = tid & 63, w = tid >> 6;
    int v[16]; int s = 0;
    #pragma unroll
    for (int j = 0; j < 16; ++j) { v[j] = deg[tid * 16 + j]; s += v[j]; }
    int inc = s;
    #pragma unroll
    for (int d = 1; d < 64; d <<= 1) {
        int x = __shfl_up(inc, d, 64);
        if (lane >= d) inc += x;
    }
    if (lane == 63) wsum[w] = inc;
    __syncthreads();
    int wpre = 0;
    #pragma unroll
    for (int j = 0; j < 4; ++j) wpre += (j < w) ? wsum[j] : 0;
    int excl = wpre + inc - s;
    #pragma unroll
    for (int j = 0; j < 16; ++j) { off[tid * 16 + j] = excl; excl += v[j]; }
    if (tid == 255) off[4096] = excl;
}

// ---------------- fill: perm[e] = CSR position of edge e (off[idx2[e]] + rank)
__global__ void fill_k(const int* __restrict__ idx2, const int* __restrict__ off,
                       int* __restrict__ cursor, int* __restrict__ perm) {
    int e = blockIdx.x * 256 + threadIdx.x;
    int n = idx2[e] & (NN - 1);
    int p = atomicAdd(&cursor[n], 1);
    perm[e] = off[n] + p;
}

// ======================================================================
// main_k: BARRIER-FREE GEMM1 — both operands direct from global (L1/L2-hot),
//   zero LDS in the k-loop, fully unrolled 8-load+16-MFMA slabs the compiler
//   software-pipelines with counted vmcnt. LDS only for H redistribution.
//   4 blocks/CU (LDS 35584), 4 barriers per block total.
// ======================================================================
__launch_bounds__(256, 4)
__global__ void main_k(const bf16* __restrict__ sitesB, const bf16* __restrict__ bondsB,
                       const int* __restrict__ idx1, const int* __restrict__ idx2,
                       const int* __restrict__ cnt, const int* __restrict__ bucket,
                       const int* __restrict__ perm,
                       const bf16* __restrict__ WtA, const bf16* __restrict__ WtB,
                       const float* __restrict__ b1a, const float* __restrict__ b2a,
                       const float* __restrict__ b1b, const float* __restrict__ b2b,
                       const float* __restrict__ Wa1, const float* __restrict__ ba1,
                       const float* __restrict__ Wa2, const float* __restrict__ ba2,
                       bf16* __restrict__ eo) {
    // LDS layout (35584 B): sH1 [0,17408) | sH2 [17408,34816) | sI1/sI2/sEid [34816,35584)
    __shared__ __align__(16) char smem[35584];
    bf16* sH1 = (bf16*)smem;
    bf16* sH2 = (bf16*)(smem + MT * LDH * 2);
    int* sI1  = (int*)(smem + 34816);
    int* sI2  = (int*)(smem + 35072);
    int* sEid = (int*)(smem + 35328);

    const int tid = threadIdx.x;

    // --- XCD-pinned decode
    int blk = blockIdx.x;
    int p = blk & 7;
    const int b = p >> 1;
    int flat = ((blk >> 3) << 1) + (p & 1);

    // --- map flat tile index -> (type, tile-within-type)
    int c0 = cnt[0], c1 = cnt[1], c2 = cnt[2], c3 = cnt[3];
    int n0 = (c0 + MT - 1) / MT, n1 = (c1 + MT - 1) / MT,
        n2 = (c2 + MT - 1) / MT, n3 = (c3 + MT - 1) / MT;
    int t, ti, cT;
    if (flat < n0)                { t = 0; ti = flat;                cT = c0; }
    else if (flat < n0+n1)        { t = 1; ti = flat - n0;           cT = c1; }
    else if (flat < n0+n1+n2)     { t = 2; ti = flat - n0 - n1;      cT = c2; }
    else if (flat < n0+n1+n2+n3)  { t = 3; ti = flat - n0 - n1 - n2; cT = c3; }
    else return;                  // uniform early-exit before any barrier
    const int base = ti * MT;
    const int nvalid = min(MT, cT - base);

    // --- gate metadata (4 threads per edge; m == tid>>2)
    const int mG  = tid >> 2;
    const int rrG = min(mG, max(nvalid - 1, 0));
    const int eG  = bucket[t * NE + base + rrG] & (NE - 1);
    const int prm = perm[eG] & (NE - 1);

    // --- edge tables in LDS (needed per-frag-row below)
    if (tid < MT) {
        int rr = min(tid, max(nvalid - 1, 0));
        int e = bucket[t * NE + base + rr] & (NE - 1);
        sEid[tid] = e;
        sI1[tid] = idx1[e] & (NN - 1);
        sI2[tid] = idx2[e] & (NN - 1);
    }
    __syncthreads();   // barrier 1

    const int wv = tid >> 6;
    const int lane = tid & 63;
    const int br = wv >> 1;          // branch
    const int nh = wv & 1;           // column half within branch
    const int lr = lane & 15;
    const int quad = lane >> 4;
    const int lk = quad * 8;
    const int colbase = nh * 64;
    const int lodd = lane & 1;

    // --- per-lane u32 element offsets (SGPR-base + voffset form)
    const unsigned sbase = (unsigned)b * NN;
    unsigned oA1[4], oA2[4], oBo[4], oB[4];
    #pragma unroll
    for (int mt = 0; mt < 4; ++mt) {
        int rw = mt * 16 + lr;
        oA1[mt] = (sbase + (unsigned)sI1[rw]) * DIN + lk;
        oA2[mt] = (sbase + (unsigned)sI2[rw]) * DIN + lk;
        oBo[mt] = ((unsigned)b * NE + (unsigned)sEid[rw]) * DB + lk;
    }
    #pragma unroll
    for (int nt = 0; nt < 4; ++nt) {
        int cc = br * 128 + colbase + nt * 16 + lr;
        oB[nt] = ((unsigned)t * 256 + (unsigned)cc) * DCAT + lk;
    }

    // --- layer 1 GEMM: 10 slabs, ZERO barriers, pure load+MFMA (compiler pipelines)
    floatx4 acc[4][4];
    #pragma unroll
    for (int mt = 0; mt < 4; ++mt)
        #pragma unroll
        for (int nt = 0; nt < 4; ++nt)
            acc[mt][nt] = (floatx4){0.f, 0.f, 0.f, 0.f};

    #pragma unroll
    for (int ks = 0; ks < 10; ++ks) {
        bf16x8 aF[4], bF[4];
        #pragma unroll
        for (int mt = 0; mt < 4; ++mt) {
            aF[mt] = (ks < 4) ? *(const bf16x8*)(sitesB + oA1[mt] + ks * 32)
                   : (ks < 8) ? *(const bf16x8*)(sitesB + oA2[mt] + (ks - 4) * 32)
                              : *(const bf16x8*)(bondsB + oBo[mt] + (ks - 8) * 32);
        }
        #pragma unroll
        for (int nt = 0; nt < 4; ++nt)
            bF[nt] = *(const bf16x8*)(WtA + oB[nt] + ks * 32);
        #pragma unroll
        for (int nt = 0; nt < 4; ++nt)
            #pragma unroll
            for (int mt = 0; mt < 4; ++mt)
                acc[mt][nt] = __builtin_amdgcn_mfma_f32_16x16x32_bf16(aF[mt], bF[nt], acc[mt][nt], 0, 0, 0);
    }

    // --- bias + lrelu -> bf16 H tile in LDS (no barrier needed before: sH untouched so far)
    bf16* sH = (br == 0) ? sH1 : sH2;
    const float* biasA = ((br == 0) ? b1a : b2a) + t * DOUT;
    #pragma unroll
    for (int nt = 0; nt < 4; ++nt) {
        int c = colbase + nt * 16 + lr;
        int cpair = c & ~1;
        float bias = biasA[c];
        #pragma unroll
        for (int mt = 0; mt < 4; ++mt) {
            float v[4], x[4];
            #pragma unroll
            for (int rg = 0; rg < 4; ++rg) {
                float u = acc[mt][nt][rg] + bias;
                v[rg] = u > 0.f ? u : 0.01f * u;
            }
            #pragma unroll
            for (int rg = 0; rg < 4; ++rg) x[rg] = __shfl_xor(v[rg], 1);
            int r0 = mt * 16 + quad * 4 + lodd * 2;
            float lo0 = lodd ? x[2] : v[0], hi0 = lodd ? v[2] : x[0];
            float lo1 = lodd ? x[3] : v[1], hi1 = lodd ? v[3] : x[1];
            *(bf16x2*)(&sH[r0 * LDH + cpair])       = (bf16x2){ (bf16)lo0, (bf16)hi0 };
            *(bf16x2*)(&sH[(r0 + 1) * LDH + cpair]) = (bf16x2){ (bf16)lo1, (bf16)hi1 };
        }
    }
    __syncthreads();   // barrier 2: H complete

    // --- layer 2 GEMM: A = own-branch H from LDS, B direct from global (L2-hot, 64KB/type)
    floatx4 acc2[4][4];
    #pragma unroll
    for (int mt = 0; mt < 4; ++mt)
        #pragma unroll
        for (int nt = 0; nt < 4; ++nt)
            acc2[mt][nt] = (floatx4){0.f, 0.f, 0.f, 0.f};

    const bf16* sHa = (br == 0) ? sH1 : sH2;
    const bf16* WtB_w = WtB + (size_t)(t * 256 + br * 128 + colbase) * DOUT + lk;
    #pragma unroll
    for (int ks = 0; ks < 4; ++ks) {
        bf16x8 aF[4];
        #pragma unroll
        for (int mt = 0; mt < 4; ++mt)
            aF[mt] = *(const bf16x8*)(&sHa[(mt * 16 + lr) * LDH + ks * 32 + lk]);
        #pragma unroll
        for (int nt = 0; nt < 4; ++nt) {
            bf16x8 bF = *(const bf16x8*)(&WtB_w[(size_t)(nt * 16 + lr) * DOUT + ks * 32]);
            #pragma unroll
            for (int mt = 0; mt < 4; ++mt)
                acc2[mt][nt] = __builtin_amdgcn_mfma_f32_16x16x32_bf16(aF[mt], bF, acc2[mt][nt], 0, 0, 0);
        }
    }
    __syncthreads();   // barrier 3: all waves done READING sH before overwrite

    // --- bias + lrelu -> final per-branch outputs back into sH (paired b32 stores)
    const float* biasB = ((br == 0) ? b1b : b2b) + t * DOUT;
    #pragma unroll
    for (int nt = 0; nt < 4; ++nt) {
        int c = colbase + nt * 16 + lr;
        int cpair = c & ~1;
        float bias = biasB[c];
        #pragma unroll
        for (int mt = 0; mt < 4; ++mt) {
            float v[4], x[4];
            #pragma unroll
            for (int rg = 0; rg < 4; ++rg) {
                float u = acc2[mt][nt][rg] + bias;
                v[rg] = u > 0.f ? u : 0.01f * u;
            }
            #pragma unroll
            for (int rg = 0; rg < 4; ++rg) x[rg] = __shfl_xor(v[rg], 1);
            int r0 = mt * 16 + quad * 4 + lodd * 2;
            float lo0 = lodd ? x[2] : v[0], hi0 = lodd ? v[2] : x[0];
            float lo1 = lodd ? x[3] : v[1], hi1 = lodd ? v[3] : x[1];
            *(bf16x2*)(&sH[r0 * LDH + cpair])       = (bf16x2){ (bf16)lo0, (bf16)hi0 };
            *(bf16x2*)(&sH[(r0 + 1) * LDH + cpair]) = (bf16x2){ (bf16)lo1, (bf16)hi1 };
        }
    }
    __syncthreads();   // barrier 4

    // --- gate + store g1+g2 per edge at its CSR slot (vectorized LDS reads, Wa from global)
    {
        int m = mG;                  // tid >> 2
        int q = tid & 3;
        float d1 = 0.f, d2 = 0.f;
        #pragma unroll
        for (int j = 0; j < 4; ++j) {
            bf16x8 h1 = *(const bf16x8*)(&sH1[m * LDH + q * 32 + j * 8]);
            bf16x8 h2 = *(const bf16x8*)(&sH2[m * LDH + q * 32 + j * 8]);
            float4 wa = *(const float4*)(&Wa1[q * 32 + j * 8]);
            float4 wb = *(const float4*)(&Wa1[q * 32 + j * 8 + 4]);
            float4 va = *(const float4*)(&Wa2[q * 32 + j * 8]);
            float4 vb = *(const float4*)(&Wa2[q * 32 + j * 8 + 4]);
            d1 += (float)h1[0] * wa.x; d1 += (float)h1[1] * wa.y;
            d1 += (float)h1[2] * wa.z; d1 += (float)h1[3] * wa.w;
            d1 += (float)h1[4] * wb.x; d1 += (float)h1[5] * wb.y;
            d1 += (float)h1[6] * wb.z; d1 += (float)h1[7] * wb.w;
            d2 += (float)h2[0] * va.x; d2 += (float)h2[1] * va.y;
            d2 += (float)h2[2] * va.z; d2 += (float)h2[3] * va.w;
            d2 += (float)h2[4] * vb.x; d2 += (float)h2[5] * vb.y;
            d2 += (float)h2[6] * vb.z; d2 += (float)h2[7] * vb.w;
        }
        d1 += __shfl_xor(d1, 1); d1 += __shfl_xor(d1, 2);
        d2 += __shfl_xor(d2, 1); d2 += __shfl_xor(d2, 2);
        d1 = fminf(fmaxf(d1 + ba1[0], -30.f), 30.f);
        d2 = fminf(fmaxf(d2 + ba2[0], -30.f), 30.f);
        float s1 = 1.f / (1.f + __expf(-d1));
        float s2 = 1.f / (1.f + __expf(-d2));
        if (m < nvalid) {
            bf16* dst = eo + ((size_t)b * NE + prm) * DOUT;
            #pragma unroll
            for (int j = 0; j < 4; ++j) {
                int cc = (q + 4 * j) * 8;
                bf16x8 h1 = *(const bf16x8*)(&sH1[m * LDH + cc]);
                bf16x8 h2 = *(const bf16x8*)(&sH2[m * LDH + cc]);
                bf16x8 w;
                #pragma unroll
                for (int c = 0; c < 8; ++c)
                    w[c] = (bf16)(s1 * (float)h1[c] + s2 * (float)h2[c]);
                *(bf16x8*)(dst + cc) = w;
            }
        }
    }
}

// ---------------- CSR gather: vectorized bf16x8 rows, 16 rows in flight, LDS partial reduce
__global__ void gather_k(const bf16* __restrict__ eo, const int* __restrict__ off,
                         float* __restrict__ out) {
    __shared__ float part[16 * 128];
    int tid = threadIdx.x;
    int g = tid >> 4;            // row group 0..15
    int cseg = tid & 15;         // column segment (8 cols each)
    int n = blockIdx.x;
    int b = blockIdx.y;
    int o0 = off[n], o1 = off[n + 1];
    const bf16* base = eo + (size_t)b * NE * DOUT + cseg * 8;
    float a[8] = {0.f, 0.f, 0.f, 0.f, 0.f, 0.f, 0.f, 0.f};
    for (int r = o0 + g; r < o1; r += 16) {
        bf16x8 v = *(const bf16x8*)(base + (size_t)r * DOUT);
        #pragma unroll
        for (int j = 0; j < 8; ++j) a[j] += (float)v[j];
    }
    #pragma unroll
    for (int j = 0; j < 8; ++j) part[g * 128 + cseg * 8 + j] = a[j];
    __syncthreads();
    if (tid < 128) {
        float s = 0.f;
        #pragma unroll
        for (int g2 = 0; g2 < 16; ++g2) s += part[g2 * 128 + tid];
        out[((size_t)b * NN + n) * DOUT + tid] = s;
    }
}

extern "C" void kernel_launch(void* const* d_in, const int* in_sizes, int n_in,
                              void* d_out, int out_size, void* d_ws, size_t ws_size,
                              hipStream_t stream) {
    const float* sites = (const float*)d_in[0];
    const float* bonds = (const float*)d_in[1];
    const int*   idx1  = (const int*)d_in[2];
    const int*   idx2  = (const int*)d_in[3];
    const int*   uc    = (const int*)d_in[4];
    const float* W1a = (const float*)d_in[5];
    const float* b1a = (const float*)d_in[6];
    const float* W1b = (const float*)d_in[7];
    const float* b1b = (const float*)d_in[8];
    const float* W2a = (const float*)d_in[9];
    const float* b2a = (const float*)d_in[10];
    const float* W2b = (const float*)d_in[11];
    const float* b2b = (const float*)d_in[12];
    const float* Wa1 = (const float*)d_in[13];
    const float* ba1 = (const float*)d_in[14];
    const float* Wa2 = (const float*)d_in[15];
    const float* ba2 = (const float*)d_in[16];
    float* out = (float*)d_out;

    char* ws = (char*)d_ws;
    size_t o_cnt    = 0;
    size_t o_deg    = 64;
    size_t o_cursor = o_deg + NN * 4;
    size_t o_off    = o_cursor + NN * 4;            // 32832B = NZERO*4
    size_t o_bucket = o_off + (NN + 16) * 4;
    size_t o_perm   = o_bucket + (size_t)NT * NE * 4;
    size_t o_wta    = o_perm + (size_t)NE * 4;
    size_t o_wtb    = o_wta + (size_t)NA * 2;
    size_t o_sitesB = o_wtb + (size_t)NB2 * 2;
    size_t o_eo     = o_sitesB + (size_t)NB * NN * DIN * 2;
    size_t need     = o_eo + (size_t)NB * NE * DOUT * 2;   // ~70.2 MiB base
    size_t o_bondsB = need;
    size_t need_full = o_bondsB + (size_t)NB * NE * DB * 2; // +32 MiB for bf16 bonds
    if (ws_size < need_full) return;   // diagnostic: out stays poisoned

    int*  cnt    = (int*)(ws + o_cnt);
    int*  deg    = (int*)(ws + o_deg);
    int*  cursor = (int*)(ws + o_cursor);
    int*  off    = (int*)(ws + o_off);
    int*  bucket = (int*)(ws + o_bucket);
    int*  perm   = (int*)(ws + o_perm);
    bf16* WtA    = (bf16*)(ws + o_wta);
    bf16* WtB    = (bf16*)(ws + o_wtb);
    bf16* sitesB = (bf16*)(ws + o_sitesB);
    bf16* eo     = (bf16*)(ws + o_eo);
    bf16* bondsB = (bf16*)(ws + o_bondsB);

    prep_k<<<(NS4 + NA + NB2 + NBO4) / 256, 256, 0, stream>>>(
        sites, bonds, W1a, W2a, W1b, W2b, sitesB, WtA, WtB, bondsB, (int*)ws);
    bucket_k<<<NE / 256, 256, 0, stream>>>(uc, idx2, cnt, deg, bucket);
    scan_k<<<1, 256, 0, stream>>>(deg, off);
    fill_k<<<NE / 256, 256, 0, stream>>>(idx2, off, cursor, perm);

    const int maxTiles = NE / MT + NT;   // 1028 tiles/batch worst case
    main_k<<<maxTiles * NB, 256, 0, stream>>>(
        sitesB, bondsB, idx1, idx2, cnt, bucket, perm, WtA, WtB,
        b1a, b2a, b1b, b2b, Wa1, ba1, Wa2, ba2, eo);

    gather_k<<<dim3(NN, NB), 256, 0, stream>>>(eo, off, out);
}

// Round 8
// 269.022 us; speedup vs baseline: 1.4917x; 1.4917x over previous
//
#include <hip/hip_runtime.h>

#define NB 4
#define NN 4096
#define NE 65536
#define DIN 128
#define DB 64
#define DOUT 128
#define NT 4
#define DCAT 320

#define MT 64               // edges per tile
#define LDH (DOUT + 8)      // 136 elems, 272 B row stride (16-div)

typedef __bf16 bf16;
typedef __bf16 bf16x2 __attribute__((ext_vector_type(2)));
typedef __bf16 bf16x4 __attribute__((ext_vector_type(4)));
typedef __bf16 bf16x8 __attribute__((ext_vector_type(8)));
typedef float floatx4 __attribute__((ext_vector_type(4)));

__device__ __forceinline__ void async16(const void* g, void* l) {
    __builtin_amdgcn_global_load_lds(
        (const __attribute__((address_space(1))) unsigned int*)g,
        (__attribute__((address_space(3))) unsigned int*)l, 16, 0, 0);
}

// ---------------- prep (+fused bucket): first 256 blocks bucket edges; rest convert/repack
#define NS4 (NB * NN * DIN / 4)      // 524288 float4 groups
#define NA  (NT * 256 * DCAT)        // 327680 WtA elems
#define NB2 (NT * 256 * DOUT)        // 131072 WtB elems
#define NBO4 (NB * NE * DB / 4)      // 4194304 bond float4 groups
#define PREP_BLOCKS ((NS4 + NA + NB2 + NBO4) / 256)   // 20224
__global__ void prep_k(const float* __restrict__ sites, const float* __restrict__ bonds,
                       const float* __restrict__ W1a, const float* __restrict__ W2a,
                       const float* __restrict__ W1b, const float* __restrict__ W2b,
                       const int* __restrict__ uc, const int* __restrict__ idx2,
                       bf16* __restrict__ sitesB,
                       bf16* __restrict__ WtA, bf16* __restrict__ WtB,
                       bf16* __restrict__ bondsB,
                       int* __restrict__ cnt, int* __restrict__ deg,
                       int* __restrict__ bucket) {
    int tid = threadIdx.x;
    if (blockIdx.x < 256) {
        // ---- bucket edges by type (LDS histogram) + degree count (cnt/deg pre-zeroed)
        __shared__ int h[NT];
        __shared__ int baseo[NT];
        if (tid < NT) h[tid] = 0;
        __syncthreads();
        int e = blockIdx.x * 256 + tid;
        int t = uc[e] & 3;
        int lp = atomicAdd(&h[t], 1);         // LDS atomic
        __syncthreads();
        if (tid < NT) baseo[tid] = atomicAdd(&cnt[tid], h[tid]);
        __syncthreads();
        bucket[t * NE + baseo[t] + lp] = e;
        atomicAdd(&deg[idx2[e] & (NN - 1)], 1);
        return;
    }
    int i = (blockIdx.x - 256) * 256 + tid;
    if (i < NS4) {
        float4 f = ((const float4*)sites)[i];
        bf16x4 h = { (bf16)f.x, (bf16)f.y, (bf16)f.z, (bf16)f.w };
        ((bf16x4*)sitesB)[i] = h;
    } else if (i < NS4 + NA) {
        int j = i - NS4;
        int k = j % DCAT;
        int n = (j / DCAT) % 256;
        int t = j / (DCAT * 256);
        float w = (n < DOUT) ? W1a[(t * DCAT + k) * DOUT + n]
                             : W2a[(t * DCAT + k) * DOUT + (n - DOUT)];
        WtA[j] = (bf16)w;
    } else if (i < NS4 + NA + NB2) {
        int j = i - NS4 - NA;
        int k = j % DOUT;
        int n = (j / DOUT) % 256;
        int t = j / (DOUT * 256);
        float w = (n < DOUT) ? W1b[(t * DOUT + k) * DOUT + n]
                             : W2b[(t * DOUT + k) * DOUT + (n - DOUT)];
        WtB[j] = (bf16)w;
    } else {
        int j = i - NS4 - NA - NB2;
        float4 f = ((const float4*)bonds)[j];
        bf16x4 h = { (bf16)f.x, (bf16)f.y, (bf16)f.z, (bf16)f.w };
        ((bf16x4*)bondsB)[j] = h;
    }
}

// ---------------- exclusive prefix sum deg[4096] -> off[4097]; also zeroes per-batch cursor
__global__ void scan_k(const int* __restrict__ deg, int* __restrict__ off,
                       int* __restrict__ cursor) {
    __shared__ int wsum[4];
    int tid = threadIdx.x;                // 256 threads, each owns 16 elems
    #pragma unroll
    for (int j = 0; j < NB * NN / 256; ++j) cursor[tid + j * 256] = 0;
    int lane = tid & 63, w = tid >> 6;
    int v[16]; int s = 0;
    #pragma unroll
    for (int j = 0; j < 16; ++j) { v[j] = deg[tid * 16 + j]; s += v[j]; }
    int inc = s;
    #pragma unroll
    for (int d = 1; d < 64; d <<= 1) {
        int x = __shfl_up(inc, d, 64);
        if (lane >= d) inc += x;
    }
    if (lane == 63) wsum[w] = inc;
    __syncthreads();
    int wpre = 0;
    #pragma unroll
    for (int j = 0; j < 4; ++j) wpre += (j < w) ? wsum[j] : 0;
    int excl = wpre + inc - s;
    #pragma unroll
    for (int j = 0; j < 16; ++j) { off[tid * 16 + j] = excl; excl += v[j]; }
    if (tid == 255) off[4096] = excl;
}

// ======================================================================
// main_k: r4 staged-dbuf structure, 4 blocks/CU, vectorized LDS epilogue/gate.
//   fill fused: CSR slot = off[n2] + atomicAdd(cursor[b][n2]) at the gate.
// ======================================================================
__launch_bounds__(256, 4)
__global__ void main_k(const bf16* __restrict__ sitesB, const bf16* __restrict__ bondsB,
                       const int* __restrict__ idx1, const int* __restrict__ idx2,
                       const int* __restrict__ cnt, const int* __restrict__ bucket,
                       const int* __restrict__ off, int* __restrict__ cursor,
                       const bf16* __restrict__ WtA, const bf16* __restrict__ WtB,
                       const float* __restrict__ b1a, const float* __restrict__ b2a,
                       const float* __restrict__ b1b, const float* __restrict__ b2b,
                       const float* __restrict__ Wa1, const float* __restrict__ ba1,
                       const float* __restrict__ Wa2, const float* __restrict__ ba2,
                       bf16* __restrict__ eo) {
    // Union layout (40960 B):
    //   phase GEMM1: sA dbuf [0,8192) + sB dbuf [8192,40960)
    //   phase GEMM2: sH1 [0,17408) + sH2 [17408,34816) + sWa [35840,36864)
    __shared__ __align__(16) char smem[40960];
    bf16* sA  = (bf16*)smem;
    bf16* sB  = (bf16*)(smem + 8192);
    bf16* sH1 = (bf16*)smem;
    bf16* sH2 = (bf16*)(smem + MT * LDH * 2);
    float* sWa = (float*)(smem + 35840);   // 256 floats: Wa1[128] ++ Wa2[128]

    const int tid = threadIdx.x;

    // --- XCD-pinned decode
    int blk = blockIdx.x;
    int p = blk & 7;
    const int b = p >> 1;
    int flat = ((blk >> 3) << 1) + (p & 1);

    // --- map flat tile index -> (type, tile-within-type)
    int c0 = cnt[0], c1 = cnt[1], c2 = cnt[2], c3 = cnt[3];
    int n0 = (c0 + MT - 1) / MT, n1 = (c1 + MT - 1) / MT,
        n2t = (c2 + MT - 1) / MT, n3 = (c3 + MT - 1) / MT;
    int t, ti, cT;
    if (flat < n0)                 { t = 0; ti = flat;                 cT = c0; }
    else if (flat < n0+n1)         { t = 1; ti = flat - n0;            cT = c1; }
    else if (flat < n0+n1+n2t)     { t = 2; ti = flat - n0 - n1;       cT = c2; }
    else if (flat < n0+n1+n2t+n3)  { t = 3; ti = flat - n0 - n1 - n2t; cT = c3; }
    else return;                  // uniform early-exit before any barrier
    const int base = ti * MT;
    const int nvalid = min(MT, cT - base);

    // --- per-thread edge metadata (rowA == gate-phase m)
    const int rowA = tid >> 2;
    const int rr = min(rowA, max(nvalid - 1, 0));
    const int e  = bucket[t * NE + base + rr] & (NE - 1);
    const int r1 = idx1[e] & (NN - 1);
    const int r2 = idx2[e] & (NN - 1);

    const int wv = tid >> 6;
    const int lane = tid & 63;
    const int br = wv >> 1;          // branch
    const int nh = wv & 1;           // column half within branch
    const int lr = lane & 15;
    const int quad = lane >> 4;
    const int lk = quad * 8;
    const int colbase = nh * 64;
    const int lodd = lane & 1;

    // --- staging bases (XOR swizzle identical to r3/r4)
    const size_t sbase = (size_t)b * NN;
    const int kseg = (tid & 3) ^ (rowA & 3);
    const bf16* pA1 = sitesB + (sbase + r1) * DIN + kseg * 8;
    const bf16* pA2 = sitesB + (sbase + r2) * DIN + kseg * 8;
    const bf16* pBo = bondsB + ((size_t)b * NE + e) * DB + kseg * 8;

    auto stageA = [&](int ks, int buf) {           // ks in 0..9
        const bf16* src = (ks < 4) ? (pA1 + ks * 32)
                        : (ks < 8) ? (pA2 + (ks - 4) * 32)
                                   : (pBo + (ks - 8) * 32);
        async16(src, smem + buf * 4096 + wv * 1024);
    };
    auto stageB1 = [&](int ks, int buf) {          // WtA, stride DCAT
        #pragma unroll
        for (int j = 0; j < 4; ++j) {
            int d = (j * 4 + wv) * 64 + lane;
            int col = d >> 2;
            int ksg = (d & 3) ^ (col & 3);
            const bf16* src = WtA + (size_t)(t * 256 + col) * DCAT + ks * 32 + ksg * 8;
            async16(src, &sB[buf * 8192 + (j * 4 + wv) * 512]);
        }
    };

    // --- layer 1 GEMM: 10 uniform ks-slabs, dbuf, 1 barrier per slab
    floatx4 acc[4][4];
    #pragma unroll
    for (int mt = 0; mt < 4; ++mt)
        #pragma unroll
        for (int nt = 0; nt < 4; ++nt)
            acc[mt][nt] = (floatx4){0.f, 0.f, 0.f, 0.f};

    stageA(0, 0);
    stageB1(0, 0);
    #pragma unroll
    for (int ks = 0; ks < 10; ++ks) {
        int buf = ks & 1;
        __syncthreads();               // drain stage(ks); all waves done compute(ks-1)
        if (ks < 9) {
            stageA(ks + 1, buf ^ 1);
            stageB1(ks + 1, buf ^ 1);
        }
        bf16x8 aF[4];
        #pragma unroll
        for (int mt = 0; mt < 4; ++mt) {
            int row = mt * 16 + lr;
            aF[mt] = *(const bf16x8*)(&sA[buf * 2048 + (row * 4 + (quad ^ (lr & 3))) * 8]);
        }
        #pragma unroll
        for (int nt = 0; nt < 4; ++nt) {
            int cc = br * 128 + colbase + nt * 16 + lr;
            bf16x8 bF = *(const bf16x8*)(&sB[buf * 8192 + (cc * 4 + (quad ^ (lr & 3))) * 8]);
            #pragma unroll
            for (int mt = 0; mt < 4; ++mt)
                acc[mt][nt] = __builtin_amdgcn_mfma_f32_16x16x32_bf16(aF[mt], bF, acc[mt][nt], 0, 0, 0);
        }
    }
    __syncthreads();   // ALL waves done with sA/sB before sH (aliased) is written

    // --- stash Wa1/Wa2 in dead LDS (region beyond sH, ex-sB tail)
    sWa[tid] = (tid < 128) ? Wa1[tid] : Wa2[tid - 128];

    // --- bias + lrelu -> bf16 H tile in LDS, paired b32 stores
    bf16* sH = (br == 0) ? sH1 : sH2;
    const float* biasA = ((br == 0) ? b1a : b2a) + t * DOUT;
    #pragma unroll
    for (int nt = 0; nt < 4; ++nt) {
        int c = colbase + nt * 16 + lr;
        int cpair = c & ~1;
        float bias = biasA[c];
        #pragma unroll
        for (int mt = 0; mt < 4; ++mt) {
            float v[4], x[4];
            #pragma unroll
            for (int rg = 0; rg < 4; ++rg) {
                float u = acc[mt][nt][rg] + bias;
                v[rg] = u > 0.f ? u : 0.01f * u;
            }
            #pragma unroll
            for (int rg = 0; rg < 4; ++rg) x[rg] = __shfl_xor(v[rg], 1);
            int r0 = mt * 16 + quad * 4 + lodd * 2;
            float lo0 = lodd ? x[2] : v[0], hi0 = lodd ? v[2] : x[0];
            float lo1 = lodd ? x[3] : v[1], hi1 = lodd ? v[3] : x[1];
            *(bf16x2*)(&sH[r0 * LDH + cpair])       = (bf16x2){ (bf16)lo0, (bf16)hi0 };
            *(bf16x2*)(&sH[(r0 + 1) * LDH + cpair]) = (bf16x2){ (bf16)lo1, (bf16)hi1 };
        }
    }
    __syncthreads();

    // --- layer 2 GEMM: A = own-branch H from LDS, B direct from global (L2-hot, 64KB/type)
    floatx4 acc2[4][4];
    #pragma unroll
    for (int mt = 0; mt < 4; ++mt)
        #pragma unroll
        for (int nt = 0; nt < 4; ++nt)
            acc2[mt][nt] = (floatx4){0.f, 0.f, 0.f, 0.f};

    const bf16* sHa = (br == 0) ? sH1 : sH2;
    const bf16* WtB_w = WtB + (size_t)(t * 256 + br * 128 + colbase) * DOUT + lk;
    #pragma unroll
    for (int ks = 0; ks < 4; ++ks) {
        bf16x8 aF[4];
        #pragma unroll
        for (int mt = 0; mt < 4; ++mt)
            aF[mt] = *(const bf16x8*)(&sHa[(mt * 16 + lr) * LDH + ks * 32 + lk]);
        #pragma unroll
        for (int nt = 0; nt < 4; ++nt) {
            bf16x8 bF = *(const bf16x8*)(&WtB_w[(size_t)(nt * 16 + lr) * DOUT + ks * 32]);
            #pragma unroll
            for (int mt = 0; mt < 4; ++mt)
                acc2[mt][nt] = __builtin_amdgcn_mfma_f32_16x16x32_bf16(aF[mt], bF, acc2[mt][nt], 0, 0, 0);
        }
    }
    __syncthreads();   // all waves done READING sH before overwrite

    // --- bias + lrelu -> final per-branch outputs back into sH (paired b32 stores)
    const float* biasB = ((br == 0) ? b1b : b2b) + t * DOUT;
    #pragma unroll
    for (int nt = 0; nt < 4; ++nt) {
        int c = colbase + nt * 16 + lr;
        int cpair = c & ~1;
        float bias = biasB[c];
        #pragma unroll
        for (int mt = 0; mt < 4; ++mt) {
            float v[4], x[4];
            #pragma unroll
            for (int rg = 0; rg < 4; ++rg) {
                float u = acc2[mt][nt][rg] + bias;
                v[rg] = u > 0.f ? u : 0.01f * u;
            }
            #pragma unroll
            for (int rg = 0; rg < 4; ++rg) x[rg] = __shfl_xor(v[rg], 1);
            int r0 = mt * 16 + quad * 4 + lodd * 2;
            float lo0 = lodd ? x[2] : v[0], hi0 = lodd ? v[2] : x[0];
            float lo1 = lodd ? x[3] : v[1], hi1 = lodd ? v[3] : x[1];
            *(bf16x2*)(&sH[r0 * LDH + cpair])       = (bf16x2){ (bf16)lo0, (bf16)hi0 };
            *(bf16x2*)(&sH[(r0 + 1) * LDH + cpair]) = (bf16x2){ (bf16)lo1, (bf16)hi1 };
        }
    }
    __syncthreads();

    // --- gate + store g1+g2 per edge at a fresh CSR slot (fused fill: off + cursor atomic)
    {
        int m = tid >> 2;            // == rowA; r2 is this thread's own node
        int q = tid & 3;
        float d1 = 0.f, d2 = 0.f;
        #pragma unroll
        for (int j = 0; j < 4; ++j) {
            bf16x8 h1 = *(const bf16x8*)(&sH1[m * LDH + q * 32 + j * 8]);
            bf16x8 h2 = *(const bf16x8*)(&sH2[m * LDH + q * 32 + j * 8]);
            float4 wa = *(const float4*)(&sWa[q * 32 + j * 8]);
            float4 wb = *(const float4*)(&sWa[q * 32 + j * 8 + 4]);
            float4 va = *(const float4*)(&sWa[128 + q * 32 + j * 8]);
            float4 vb = *(const float4*)(&sWa[128 + q * 32 + j * 8 + 4]);
            d1 += (float)h1[0] * wa.x; d1 += (float)h1[1] * wa.y;
            d1 += (float)h1[2] * wa.z; d1 += (float)h1[3] * wa.w;
            d1 += (float)h1[4] * wb.x; d1 += (float)h1[5] * wb.y;
            d1 += (float)h1[6] * wb.z; d1 += (float)h1[7] * wb.w;
            d2 += (float)h2[0] * va.x; d2 += (float)h2[1] * va.y;
            d2 += (float)h2[2] * va.z; d2 += (float)h2[3] * va.w;
            d2 += (float)h2[4] * vb.x; d2 += (float)h2[5] * vb.y;
            d2 += (float)h2[6] * vb.z; d2 += (float)h2[7] * vb.w;
        }
        d1 += __shfl_xor(d1, 1); d1 += __shfl_xor(d1, 2);
        d2 += __shfl_xor(d2, 1); d2 += __shfl_xor(d2, 2);
        d1 = fminf(fmaxf(d1 + ba1[0], -30.f), 30.f);
        d2 = fminf(fmaxf(d2 + ba2[0], -30.f), 30.f);
        float s1 = 1.f / (1.f + __expf(-d1));
        float s2 = 1.f / (1.f + __expf(-d2));
        if (m < nvalid) {
            int rank0 = 0;
            if (q == 0) rank0 = atomicAdd(&cursor[b * NN + r2], 1);
            int rank = __shfl(rank0, lane & ~3);   // broadcast q0's slot within the quad
            int prm = (off[r2] + rank) & (NE - 1);
            bf16* dst = eo + ((size_t)b * NE + prm) * DOUT;
            #pragma unroll
            for (int j = 0; j < 4; ++j) {
                int cc = (q + 4 * j) * 8;
                bf16x8 h1 = *(const bf16x8*)(&sH1[m * LDH + cc]);
                bf16x8 h2 = *(const bf16x8*)(&sH2[m * LDH + cc]);
                bf16x8 w;
                #pragma unroll
                for (int c = 0; c < 8; ++c)
                    w[c] = (bf16)(s1 * (float)h1[c] + s2 * (float)h2[c]);
                *(bf16x8*)(dst + cc) = w;
            }
        }
    }
}

// ---------------- CSR gather: 4 nodes per block, bf16x8 rows, LDS partial reduce
__global__ void gather_k(const bf16* __restrict__ eo, const int* __restrict__ off,
                         float* __restrict__ out) {
    __shared__ float part[4 * 4 * 128];   // node, row-group, col (8 KB)
    int tid = threadIdx.x;
    int nl = tid >> 6;           // node-local 0..3
    int g  = (tid >> 4) & 3;     // row group 0..3
    int cseg = tid & 15;         // column segment (8 cols each)
    int n = blockIdx.x * 4 + nl;
    int b = blockIdx.y;
    int o0 = off[n], o1 = off[n + 1];
    const bf16* base = eo + (size_t)b * NE * DOUT + cseg * 8;
    float a[8] = {0.f, 0.f, 0.f, 0.f, 0.f, 0.f, 0.f, 0.f};
    for (int r = o0 + g; r < o1; r += 4) {
        bf16x8 v = *(const bf16x8*)(base + (size_t)r * DOUT);
        #pragma unroll
        for (int j = 0; j < 8; ++j) a[j] += (float)v[j];
    }
    #pragma unroll
    for (int j = 0; j < 8; ++j) part[(nl * 4 + g) * 128 + cseg * 8 + j] = a[j];
    __syncthreads();
    // 256 threads -> 4 nodes x 128 cols, 2 cols per thread
    int c2 = (tid & 63) * 2;
    float s0 = 0.f, s1 = 0.f;
    #pragma unroll
    for (int gg = 0; gg < 4; ++gg) {
        s0 += part[(nl * 4 + gg) * 128 + c2];
        s1 += part[(nl * 4 + gg) * 128 + c2 + 1];
    }
    float2 o = { s0, s1 };
    *(float2*)(&out[((size_t)b * NN + n) * DOUT + c2]) = o;
}

extern "C" void kernel_launch(void* const* d_in, const int* in_sizes, int n_in,
                              void* d_out, int out_size, void* d_ws, size_t ws_size,
                              hipStream_t stream) {
    const float* sites = (const float*)d_in[0];
    const float* bonds = (const float*)d_in[1];
    const int*   idx1  = (const int*)d_in[2];
    const int*   idx2  = (const int*)d_in[3];
    const int*   uc    = (const int*)d_in[4];
    const float* W1a = (const float*)d_in[5];
    const float* b1a = (const float*)d_in[6];
    const float* W1b = (const float*)d_in[7];
    const float* b1b = (const float*)d_in[8];
    const float* W2a = (const float*)d_in[9];
    const float* b2a = (const float*)d_in[10];
    const float* W2b = (const float*)d_in[11];
    const float* b2b = (const float*)d_in[12];
    const float* Wa1 = (const float*)d_in[13];
    const float* ba1 = (const float*)d_in[14];
    const float* Wa2 = (const float*)d_in[15];
    const float* ba2 = (const float*)d_in[16];
    float* out = (float*)d_out;

    char* ws = (char*)d_ws;
    size_t o_cnt    = 0;                              // 16 ints (64 B)
    size_t o_deg    = 64;                             // 4096 ints
    size_t o_cursor = o_deg + NN * 4;                 // NB*NN ints (64 KiB)
    size_t o_off    = o_cursor + (size_t)NB * NN * 4; // (NN+16) ints
    size_t o_bucket = o_off + (NN + 16) * 4;
    size_t o_wta    = o_bucket + (size_t)NT * NE * 4;
    size_t o_wtb    = o_wta + (size_t)NA * 2;
    size_t o_sitesB = o_wtb + (size_t)NB2 * 2;
    size_t o_eo     = o_sitesB + (size_t)NB * NN * DIN * 2;
    size_t o_bondsB = o_eo + (size_t)NB * NE * DOUT * 2;
    size_t need     = o_bondsB + (size_t)NB * NE * DB * 2;   // ~102 MiB
    if (ws_size < need) return;   // diagnostic: out stays poisoned

    int*  cnt    = (int*)(ws + o_cnt);
    int*  deg    = (int*)(ws + o_deg);
    int*  cursor = (int*)(ws + o_cursor);
    int*  off    = (int*)(ws + o_off);
    int*  bucket = (int*)(ws + o_bucket);
    bf16* WtA    = (bf16*)(ws + o_wta);
    bf16* WtB    = (bf16*)(ws + o_wtb);
    bf16* sitesB = (bf16*)(ws + o_sitesB);
    bf16* eo     = (bf16*)(ws + o_eo);
    bf16* bondsB = (bf16*)(ws + o_bondsB);

    // zero cnt+deg (16448 B) before the fused prep+bucket launch
    hipMemsetAsync(ws, 0, 64 + (size_t)NN * 4, stream);

    prep_k<<<PREP_BLOCKS + 256, 256, 0, stream>>>(
        sites, bonds, W1a, W2a, W1b, W2b, uc, idx2,
        sitesB, WtA, WtB, bondsB, cnt, deg, bucket);
    scan_k<<<1, 256, 0, stream>>>(deg, off, cursor);

    const int maxTiles = NE / MT + NT;   // 1028 tiles/batch worst case
    main_k<<<maxTiles * NB, 256, 0, stream>>>(
        sitesB, bondsB, idx1, idx2, cnt, bucket, off, cursor, WtA, WtB,
        b1a, b2a, b1b, b2b, Wa1, ba1, Wa2, ba2, eo);

    gather_k<<<dim3(NN / 4, NB), 256, 0, stream>>>(eo, off, out);
}

// Round 9
// 262.390 us; speedup vs baseline: 1.5294x; 1.0253x over previous
//
#include <hip/hip_runtime.h>

#define NB 4
#define NN 4096
#define NE 65536
#define DIN 128
#define DB 64
#define DOUT 128
#define NT 4
#define DCAT 320

#define MT 64               // edges per tile
#define LDH (DOUT + 8)      // 136 elems, 272 B row stride (16-div)

typedef __bf16 bf16;
typedef __bf16 bf16x2 __attribute__((ext_vector_type(2)));
typedef __bf16 bf16x4 __attribute__((ext_vector_type(4)));
typedef __bf16 bf16x8 __attribute__((ext_vector_type(8)));
typedef float floatx4 __attribute__((ext_vector_type(4)));

__device__ __forceinline__ void async16(const void* g, void* l) {
    __builtin_amdgcn_global_load_lds(
        (const __attribute__((address_space(1))) unsigned int*)g,
        (__attribute__((address_space(3))) unsigned int*)l, 16, 0, 0);
}

// ---------------- prep (+fused bucket): first 256 blocks bucket edges; rest grid-stride convert
#define NS4 (NB * NN * DIN / 4)      // 524288 float4 groups
#define NA  (NT * 256 * DCAT)        // 327680 WtA elems
#define NB2 (NT * 256 * DOUT)        // 131072 WtB elems
#define NBO4 (NB * NE * DB / 4)      // 4194304 bond float4 groups
#define NCHUNK ((NS4 + NA + NB2 + NBO4) / 256)   // 20224 chunks of 256
#define PSTRIDE 4096
__global__ void prep_k(const float* __restrict__ sites, const float* __restrict__ bonds,
                       const float* __restrict__ W1a, const float* __restrict__ W2a,
                       const float* __restrict__ W1b, const float* __restrict__ W2b,
                       const int* __restrict__ uc, const int* __restrict__ idx2,
                       bf16* __restrict__ sitesB,
                       bf16* __restrict__ WtA, bf16* __restrict__ WtB,
                       bf16* __restrict__ bondsB,
                       int* __restrict__ cnt, int* __restrict__ deg,
                       int* __restrict__ bucket) {
    int tid = threadIdx.x;
    if (blockIdx.x < 256) {
        // ---- bucket edges by type (LDS histogram) + degree count (cnt/deg pre-zeroed)
        __shared__ int h[NT];
        __shared__ int baseo[NT];
        if (tid < NT) h[tid] = 0;
        __syncthreads();
        int e = blockIdx.x * 256 + tid;
        int t = uc[e] & 3;
        int lp = atomicAdd(&h[t], 1);         // LDS atomic
        __syncthreads();
        if (tid < NT) baseo[tid] = atomicAdd(&cnt[tid], h[tid]);
        __syncthreads();
        bucket[t * NE + baseo[t] + lp] = e;
        atomicAdd(&deg[idx2[e] & (NN - 1)], 1);
        return;
    }
    // ---- grid-stride conversion/repack over NCHUNK chunks
    for (int c = blockIdx.x - 256; c < NCHUNK; c += PSTRIDE) {
        int i = c * 256 + tid;
        if (i < NS4) {
            float4 f = ((const float4*)sites)[i];
            bf16x4 h = { (bf16)f.x, (bf16)f.y, (bf16)f.z, (bf16)f.w };
            ((bf16x4*)sitesB)[i] = h;
        } else if (i < NS4 + NA) {
            int j = i - NS4;
            int k = j % DCAT;
            int n = (j / DCAT) % 256;
            int t = j / (DCAT * 256);
            float w = (n < DOUT) ? W1a[(t * DCAT + k) * DOUT + n]
                                 : W2a[(t * DCAT + k) * DOUT + (n - DOUT)];
            WtA[j] = (bf16)w;
        } else if (i < NS4 + NA + NB2) {
            int j = i - NS4 - NA;
            int k = j % DOUT;
            int n = (j / DOUT) % 256;
            int t = j / (DOUT * 256);
            float w = (n < DOUT) ? W1b[(t * DOUT + k) * DOUT + n]
                                 : W2b[(t * DOUT + k) * DOUT + (n - DOUT)];
            WtB[j] = (bf16)w;
        } else {
            int j = i - NS4 - NA - NB2;
            float4 f = ((const float4*)bonds)[j];
            bf16x4 h = { (bf16)f.x, (bf16)f.y, (bf16)f.z, (bf16)f.w };
            ((bf16x4*)bondsB)[j] = h;
        }
    }
}

// ---------------- exclusive prefix sum deg[4096] -> off[4097] (cursor zeroed by memset)
__global__ void scan_k(const int* __restrict__ deg, int* __restrict__ off) {
    __shared__ int wsum[4];
    int tid = threadIdx.x;                // 256 threads, each owns 16 elems
    int lane = tid & 63, w = tid >> 6;
    int v[16]; int s = 0;
    #pragma unroll
    for (int j = 0; j < 16; ++j) { v[j] = deg[tid * 16 + j]; s += v[j]; }
    int inc = s;
    #pragma unroll
    for (int d = 1; d < 64; d <<= 1) {
        int x = __shfl_up(inc, d, 64);
        if (lane >= d) inc += x;
    }
    if (lane == 63) wsum[w] = inc;
    __syncthreads();
    int wpre = 0;
    #pragma unroll
    for (int j = 0; j < 4; ++j) wpre += (j < w) ? wsum[j] : 0;
    int excl = wpre + inc - s;
    #pragma unroll
    for (int j = 0; j < 16; ++j) { off[tid * 16 + j] = excl; excl += v[j]; }
    if (tid == 255) off[4096] = excl;
}

// ======================================================================
// main_k: r8 staged-dbuf structure, 4 blocks/CU, 3-term XOR swizzle
//   (conflict-free ds_read_b128: lanes lr,lr+4,lr+8,lr+12 now hit distinct banks)
// ======================================================================
__launch_bounds__(256, 4)
__global__ void main_k(const bf16* __restrict__ sitesB, const bf16* __restrict__ bondsB,
                       const int* __restrict__ idx1, const int* __restrict__ idx2,
                       const int* __restrict__ cnt, const int* __restrict__ bucket,
                       const int* __restrict__ off, int* __restrict__ cursor,
                       const bf16* __restrict__ WtA, const bf16* __restrict__ WtB,
                       const float* __restrict__ b1a, const float* __restrict__ b2a,
                       const float* __restrict__ b1b, const float* __restrict__ b2b,
                       const float* __restrict__ Wa1, const float* __restrict__ ba1,
                       const float* __restrict__ Wa2, const float* __restrict__ ba2,
                       bf16* __restrict__ eo) {
    // Union layout (40960 B):
    //   phase GEMM1: sA dbuf [0,8192) + sB dbuf [8192,40960)
    //   phase GEMM2: sH1 [0,17408) + sH2 [17408,34816) + sWa [35840,36864)
    __shared__ __align__(16) char smem[40960];
    bf16* sA  = (bf16*)smem;
    bf16* sB  = (bf16*)(smem + 8192);
    bf16* sH1 = (bf16*)smem;
    bf16* sH2 = (bf16*)(smem + MT * LDH * 2);
    float* sWa = (float*)(smem + 35840);   // 256 floats: Wa1[128] ++ Wa2[128]

    const int tid = threadIdx.x;

    // --- XCD-pinned decode
    int blk = blockIdx.x;
    int p = blk & 7;
    const int b = p >> 1;
    int flat = ((blk >> 3) << 1) + (p & 1);

    // --- map flat tile index -> (type, tile-within-type)
    int c0 = cnt[0], c1 = cnt[1], c2 = cnt[2], c3 = cnt[3];
    int n0 = (c0 + MT - 1) / MT, n1 = (c1 + MT - 1) / MT,
        n2t = (c2 + MT - 1) / MT, n3 = (c3 + MT - 1) / MT;
    int t, ti, cT;
    if (flat < n0)                 { t = 0; ti = flat;                 cT = c0; }
    else if (flat < n0+n1)         { t = 1; ti = flat - n0;            cT = c1; }
    else if (flat < n0+n1+n2t)     { t = 2; ti = flat - n0 - n1;       cT = c2; }
    else if (flat < n0+n1+n2t+n3)  { t = 3; ti = flat - n0 - n1 - n2t; cT = c3; }
    else return;                  // uniform early-exit before any barrier
    const int base = ti * MT;
    const int nvalid = min(MT, cT - base);

    // --- per-thread edge metadata (rowA == gate-phase m)
    const int rowA = tid >> 2;
    const int rr = min(rowA, max(nvalid - 1, 0));
    const int e  = bucket[t * NE + base + rr] & (NE - 1);
    const int r1 = idx1[e] & (NN - 1);
    const int r2 = idx2[e] & (NN - 1);

    const int wv = tid >> 6;
    const int lane = tid & 63;
    const int br = wv >> 1;          // branch
    const int nh = wv & 1;           // column half within branch
    const int lr = lane & 15;
    const int quad = lane >> 4;
    const int lk = quad * 8;
    const int colbase = nh * 64;
    const int lodd = lane & 1;

    // --- staging bases (3-term XOR swizzle: conflict-free b128 reads)
    const size_t sbase = (size_t)b * NN;
    const int kseg = (tid & 3) ^ (rowA & 3) ^ ((rowA >> 2) & 3);
    const bf16* pA1 = sitesB + (sbase + r1) * DIN + kseg * 8;
    const bf16* pA2 = sitesB + (sbase + r2) * DIN + kseg * 8;
    const bf16* pBo = bondsB + ((size_t)b * NE + e) * DB + kseg * 8;

    auto stageA = [&](int ks, int buf) {           // ks in 0..9
        const bf16* src = (ks < 4) ? (pA1 + ks * 32)
                        : (ks < 8) ? (pA2 + (ks - 4) * 32)
                                   : (pBo + (ks - 8) * 32);
        async16(src, smem + buf * 4096 + wv * 1024);
    };
    auto stageB1 = [&](int ks, int buf) {          // WtA, stride DCAT
        #pragma unroll
        for (int j = 0; j < 4; ++j) {
            int d = (j * 4 + wv) * 64 + lane;
            int col = d >> 2;
            int ksg = (d & 3) ^ (col & 3) ^ ((col >> 2) & 3);
            const bf16* src = WtA + (size_t)(t * 256 + col) * DCAT + ks * 32 + ksg * 8;
            async16(src, &sB[buf * 8192 + (j * 4 + wv) * 512]);
        }
    };

    // read-side swizzle slot (row&3 == lr&3, (row>>2)&3 == (lr>>2)&3 for A-rows and B-cols)
    const int slot = quad ^ (lr & 3) ^ ((lr >> 2) & 3);

    // --- layer 1 GEMM: 10 uniform ks-slabs, dbuf, 1 barrier per slab
    floatx4 acc[4][4];
    #pragma unroll
    for (int mt = 0; mt < 4; ++mt)
        #pragma unroll
        for (int nt = 0; nt < 4; ++nt)
            acc[mt][nt] = (floatx4){0.f, 0.f, 0.f, 0.f};

    stageA(0, 0);
    stageB1(0, 0);
    #pragma unroll
    for (int ks = 0; ks < 10; ++ks) {
        int buf = ks & 1;
        __syncthreads();               // drain stage(ks); all waves done compute(ks-1)
        if (ks < 9) {
            stageA(ks + 1, buf ^ 1);
            stageB1(ks + 1, buf ^ 1);
        }
        bf16x8 aF[4];
        #pragma unroll
        for (int mt = 0; mt < 4; ++mt) {
            int row = mt * 16 + lr;
            aF[mt] = *(const bf16x8*)(&sA[buf * 2048 + (row * 4 + slot) * 8]);
        }
        #pragma unroll
        for (int nt = 0; nt < 4; ++nt) {
            int cc = br * 128 + colbase + nt * 16 + lr;
            bf16x8 bF = *(const bf16x8*)(&sB[buf * 8192 + (cc * 4 + slot) * 8]);
            #pragma unroll
            for (int mt = 0; mt < 4; ++mt)
                acc[mt][nt] = __builtin_amdgcn_mfma_f32_16x16x32_bf16(aF[mt], bF, acc[mt][nt], 0, 0, 0);
        }
    }
    __syncthreads();   // ALL waves done with sA/sB before sH (aliased) is written

    // --- stash Wa1/Wa2 in dead LDS (region beyond sH, ex-sB tail)
    sWa[tid] = (tid < 128) ? Wa1[tid] : Wa2[tid - 128];

    // --- bias + lrelu -> bf16 H tile in LDS, paired b32 stores
    bf16* sH = (br == 0) ? sH1 : sH2;
    const float* biasA = ((br == 0) ? b1a : b2a) + t * DOUT;
    #pragma unroll
    for (int nt = 0; nt < 4; ++nt) {
        int c = colbase + nt * 16 + lr;
        int cpair = c & ~1;
        float bias = biasA[c];
        #pragma unroll
        for (int mt = 0; mt < 4; ++mt) {
            float v[4], x[4];
            #pragma unroll
            for (int rg = 0; rg < 4; ++rg) {
                float u = acc[mt][nt][rg] + bias;
                v[rg] = u > 0.f ? u : 0.01f * u;
            }
            #pragma unroll
            for (int rg = 0; rg < 4; ++rg) x[rg] = __shfl_xor(v[rg], 1);
            int r0 = mt * 16 + quad * 4 + lodd * 2;
            float lo0 = lodd ? x[2] : v[0], hi0 = lodd ? v[2] : x[0];
            float lo1 = lodd ? x[3] : v[1], hi1 = lodd ? v[3] : x[1];
            *(bf16x2*)(&sH[r0 * LDH + cpair])       = (bf16x2){ (bf16)lo0, (bf16)hi0 };
            *(bf16x2*)(&sH[(r0 + 1) * LDH + cpair]) = (bf16x2){ (bf16)lo1, (bf16)hi1 };
        }
    }
    __syncthreads();

    // --- layer 2 GEMM: A = own-branch H from LDS, B direct from global (L2-hot, 64KB/type)
    floatx4 acc2[4][4];
    #pragma unroll
    for (int mt = 0; mt < 4; ++mt)
        #pragma unroll
        for (int nt = 0; nt < 4; ++nt)
            acc2[mt][nt] = (floatx4){0.f, 0.f, 0.f, 0.f};

    const bf16* sHa = (br == 0) ? sH1 : sH2;
    const bf16* WtB_w = WtB + (size_t)(t * 256 + br * 128 + colbase) * DOUT + lk;
    #pragma unroll
    for (int ks = 0; ks < 4; ++ks) {
        bf16x8 aF[4];
        #pragma unroll
        for (int mt = 0; mt < 4; ++mt)
            aF[mt] = *(const bf16x8*)(&sHa[(mt * 16 + lr) * LDH + ks * 32 + lk]);
        #pragma unroll
        for (int nt = 0; nt < 4; ++nt) {
            bf16x8 bF = *(const bf16x8*)(&WtB_w[(size_t)(nt * 16 + lr) * DOUT + ks * 32]);
            #pragma unroll
            for (int mt = 0; mt < 4; ++mt)
                acc2[mt][nt] = __builtin_amdgcn_mfma_f32_16x16x32_bf16(aF[mt], bF, acc2[mt][nt], 0, 0, 0);
        }
    }
    __syncthreads();   // all waves done READING sH before overwrite

    // --- bias + lrelu -> final per-branch outputs back into sH (paired b32 stores)
    const float* biasB = ((br == 0) ? b1b : b2b) + t * DOUT;
    #pragma unroll
    for (int nt = 0; nt < 4; ++nt) {
        int c = colbase + nt * 16 + lr;
        int cpair = c & ~1;
        float bias = biasB[c];
        #pragma unroll
        for (int mt = 0; mt < 4; ++mt) {
            float v[4], x[4];
            #pragma unroll
            for (int rg = 0; rg < 4; ++rg) {
                float u = acc2[mt][nt][rg] + bias;
                v[rg] = u > 0.f ? u : 0.01f * u;
            }
            #pragma unroll
            for (int rg = 0; rg < 4; ++rg) x[rg] = __shfl_xor(v[rg], 1);
            int r0 = mt * 16 + quad * 4 + lodd * 2;
            float lo0 = lodd ? x[2] : v[0], hi0 = lodd ? v[2] : x[0];
            float lo1 = lodd ? x[3] : v[1], hi1 = lodd ? v[3] : x[1];
            *(bf16x2*)(&sH[r0 * LDH + cpair])       = (bf16x2){ (bf16)lo0, (bf16)hi0 };
            *(bf16x2*)(&sH[(r0 + 1) * LDH + cpair]) = (bf16x2){ (bf16)lo1, (bf16)hi1 };
        }
    }
    __syncthreads();

    // --- gate + store g1+g2 per edge at a fresh CSR slot (fused fill: off + cursor atomic)
    {
        int m = tid >> 2;            // == rowA; r2 is this thread's own node
        int q = tid & 3;
        float d1 = 0.f, d2 = 0.f;
        #pragma unroll
        for (int j = 0; j < 4; ++j) {
            bf16x8 h1 = *(const bf16x8*)(&sH1[m * LDH + q * 32 + j * 8]);
            bf16x8 h2 = *(const bf16x8*)(&sH2[m * LDH + q * 32 + j * 8]);
            float4 wa = *(const float4*)(&sWa[q * 32 + j * 8]);
            float4 wb = *(const float4*)(&sWa[q * 32 + j * 8 + 4]);
            float4 va = *(const float4*)(&sWa[128 + q * 32 + j * 8]);
            float4 vb = *(const float4*)(&sWa[128 + q * 32 + j * 8 + 4]);
            d1 += (float)h1[0] * wa.x; d1 += (float)h1[1] * wa.y;
            d1 += (float)h1[2] * wa.z; d1 += (float)h1[3] * wa.w;
            d1 += (float)h1[4] * wb.x; d1 += (float)h1[5] * wb.y;
            d1 += (float)h1[6] * wb.z; d1 += (float)h1[7] * wb.w;
            d2 += (float)h2[0] * va.x; d2 += (float)h2[1] * va.y;
            d2 += (float)h2[2] * va.z; d2 += (float)h2[3] * va.w;
            d2 += (float)h2[4] * vb.x; d2 += (float)h2[5] * vb.y;
            d2 += (float)h2[6] * vb.z; d2 += (float)h2[7] * vb.w;
        }
        d1 += __shfl_xor(d1, 1); d1 += __shfl_xor(d1, 2);
        d2 += __shfl_xor(d2, 1); d2 += __shfl_xor(d2, 2);
        d1 = fminf(fmaxf(d1 + ba1[0], -30.f), 30.f);
        d2 = fminf(fmaxf(d2 + ba2[0], -30.f), 30.f);
        float s1 = 1.f / (1.f + __expf(-d1));
        float s2 = 1.f / (1.f + __expf(-d2));
        if (m < nvalid) {
            int rank0 = 0;
            if (q == 0) rank0 = atomicAdd(&cursor[b * NN + r2], 1);
            int rank = __shfl(rank0, lane & ~3);   // broadcast q0's slot within the quad
            int prm = (off[r2] + rank) & (NE - 1);
            bf16* dst = eo + ((size_t)b * NE + prm) * DOUT;
            #pragma unroll
            for (int j = 0; j < 4; ++j) {
                int cc = (q + 4 * j) * 8;
                bf16x8 h1 = *(const bf16x8*)(&sH1[m * LDH + cc]);
                bf16x8 h2 = *(const bf16x8*)(&sH2[m * LDH + cc]);
                bf16x8 w;
                #pragma unroll
                for (int c = 0; c < 8; ++c)
                    w[c] = (bf16)(s1 * (float)h1[c] + s2 * (float)h2[c]);
                *(bf16x8*)(dst + cc) = w;
            }
        }
    }
}

// ---------------- CSR gather: 4 nodes per block, bf16x8 rows, LDS partial reduce
__global__ void gather_k(const bf16* __restrict__ eo, const int* __restrict__ off,
                         float* __restrict__ out) {
    __shared__ float part[4 * 4 * 128];   // node, row-group, col (8 KB)
    int tid = threadIdx.x;
    int nl = tid >> 6;           // node-local 0..3
    int g  = (tid >> 4) & 3;     // row group 0..3
    int cseg = tid & 15;         // column segment (8 cols each)
    int n = blockIdx.x * 4 + nl;
    int b = blockIdx.y;
    int o0 = off[n], o1 = off[n + 1];
    const bf16* base = eo + (size_t)b * NE * DOUT + cseg * 8;
    float a[8] = {0.f, 0.f, 0.f, 0.f, 0.f, 0.f, 0.f, 0.f};
    for (int r = o0 + g; r < o1; r += 4) {
        bf16x8 v = *(const bf16x8*)(base + (size_t)r * DOUT);
        #pragma unroll
        for (int j = 0; j < 8; ++j) a[j] += (float)v[j];
    }
    #pragma unroll
    for (int j = 0; j < 8; ++j) part[(nl * 4 + g) * 128 + cseg * 8 + j] = a[j];
    __syncthreads();
    // 256 threads -> 4 nodes x 128 cols, 2 cols per thread
    int c2 = (tid & 63) * 2;
    float s0 = 0.f, s1 = 0.f;
    #pragma unroll
    for (int gg = 0; gg < 4; ++gg) {
        s0 += part[(nl * 4 + gg) * 128 + c2];
        s1 += part[(nl * 4 + gg) * 128 + c2 + 1];
    }
    float2 o = { s0, s1 };
    *(float2*)(&out[((size_t)b * NN + n) * DOUT + c2]) = o;
}

extern "C" void kernel_launch(void* const* d_in, const int* in_sizes, int n_in,
                              void* d_out, int out_size, void* d_ws, size_t ws_size,
                              hipStream_t stream) {
    const float* sites = (const float*)d_in[0];
    const float* bonds = (const float*)d_in[1];
    const int*   idx1  = (const int*)d_in[2];
    const int*   idx2  = (const int*)d_in[3];
    const int*   uc    = (const int*)d_in[4];
    const float* W1a = (const float*)d_in[5];
    const float* b1a = (const float*)d_in[6];
    const float* W1b = (const float*)d_in[7];
    const float* b1b = (const float*)d_in[8];
    const float* W2a = (const float*)d_in[9];
    const float* b2a = (const float*)d_in[10];
    const float* W2b = (const float*)d_in[11];
    const float* b2b = (const float*)d_in[12];
    const float* Wa1 = (const float*)d_in[13];
    const float* ba1 = (const float*)d_in[14];
    const float* Wa2 = (const float*)d_in[15];
    const float* ba2 = (const float*)d_in[16];
    float* out = (float*)d_out;

    char* ws = (char*)d_ws;
    size_t o_cnt    = 0;                              // 16 ints (64 B)
    size_t o_deg    = 64;                             // 4096 ints
    size_t o_cursor = o_deg + NN * 4;                 // NB*NN ints (64 KiB)
    size_t o_off    = o_cursor + (size_t)NB * NN * 4; // (NN+16) ints
    size_t o_bucket = o_off + (NN + 16) * 4;
    size_t o_wta    = o_bucket + (size_t)NT * NE * 4;
    size_t o_wtb    = o_wta + (size_t)NA * 2;
    size_t o_sitesB = o_wtb + (size_t)NB2 * 2;
    size_t o_eo     = o_sitesB + (size_t)NB * NN * DIN * 2;
    size_t o_bondsB = o_eo + (size_t)NB * NE * DOUT * 2;
    size_t need     = o_bondsB + (size_t)NB * NE * DB * 2;   // ~102 MiB
    if (ws_size < need) return;   // diagnostic: out stays poisoned

    int*  cnt    = (int*)(ws + o_cnt);
    int*  deg    = (int*)(ws + o_deg);
    int*  cursor = (int*)(ws + o_cursor);
    int*  off    = (int*)(ws + o_off);
    int*  bucket = (int*)(ws + o_bucket);
    bf16* WtA    = (bf16*)(ws + o_wta);
    bf16* WtB    = (bf16*)(ws + o_wtb);
    bf16* sitesB = (bf16*)(ws + o_sitesB);
    bf16* eo     = (bf16*)(ws + o_eo);
    bf16* bondsB = (bf16*)(ws + o_bondsB);

    // zero cnt + deg + cursor (contiguous: 64 + 16 KiB + 64 KiB) in one memset
    hipMemsetAsync(ws, 0, 64 + (size_t)NN * 4 + (size_t)NB * NN * 4, stream);

    prep_k<<<PSTRIDE + 256, 256, 0, stream>>>(
        sites, bonds, W1a, W2a, W1b, W2b, uc, idx2,
        sitesB, WtA, WtB, bondsB, cnt, deg, bucket);
    scan_k<<<1, 256, 0, stream>>>(deg, off);

    const int maxTiles = NE / MT + NT;   // 1028 tiles/batch worst case
    main_k<<<maxTiles * NB, 256, 0, stream>>>(
        sitesB, bondsB, idx1, idx2, cnt, bucket, off, cursor, WtA, WtB,
        b1a, b2a, b1b, b2b, Wa1, ba1, Wa2, ba2, eo);

    gather_k<<<dim3(NN / 4, NB), 256, 0, stream>>>(eo, off, out);
}